// Round 10
// baseline (248.269 us; speedup 1.0000x reference)
//
#include <hip/hip_runtime.h>

#define FDIM 1024
#define NLAYERS 4

typedef float v4f __attribute__((ext_vector_type(4)));

// ---------------------------------------------------------------------------
// Algebraic form of the cross layer:
//   x_{i+1} = x0*s_i + B_i + x_i,  s_i = dot(x_i, W_i)
// =>  x_i = alpha_i * x0 + beta_i,   beta_i = sum_{k<i} B_k  (row-independent)
//     s_i = alpha_i * d_i + e_i,     d_i = dot(x0, W_i)  (per-row)
//                                    e_i = dot(beta_i, W_i)  (row-independent)
//     alpha_{i+1} = alpha_i + s_i,   alpha_0 = 1
//   out = alpha_4 * x0 + SB,         SB = beta_4 = B0+B1+B2+B3
//
// Fully fused: each wave recomputes e1..e3 (row-independent, redundant but
// L1-hot and hidden under the HBM stream) inside the same 7-wide butterfly
// reduce used for the per-row d0..d3. No pre-kernel, no workspace.
// ---------------------------------------------------------------------------

// One wave (64 lanes) per row; 4 waves per 256-thread block.
// x/out use non-temporal accesses (streamed once); Ws/Bs stay cached.
__global__ __launch_bounds__(256) void cross_net_fused(
    const float* __restrict__ x, const float* __restrict__ Ws,
    const float* __restrict__ Bs, float* __restrict__ out, int nrows) {
  const int wave = threadIdx.x >> 6;
  const int lane = threadIdx.x & 63;
  const int row = blockIdx.x * 4 + wave;
  if (row >= nrows) return;

  const float* xr = x + (size_t)row * FDIM;
  v4f x0[4];
#pragma unroll
  for (int c = 0; c < 4; ++c)
    x0[c] = __builtin_nontemporal_load(
        reinterpret_cast<const v4f*>(xr + c * 256 + lane * 4));

  float d0 = 0.f, d1 = 0.f, d2 = 0.f, d3 = 0.f;
  float e1 = 0.f, e2 = 0.f, e3 = 0.f;
  v4f sb[4];  // SB = B0+B1+B2+B3 at this lane's columns, kept in registers

#pragma unroll
  for (int c = 0; c < 4; ++c) {
    const int off = c * 256 + lane * 4;
    const v4f b0 = *reinterpret_cast<const v4f*>(Bs + 0 * FDIM + off);
    const v4f b1 = *reinterpret_cast<const v4f*>(Bs + 1 * FDIM + off);
    const v4f b2 = *reinterpret_cast<const v4f*>(Bs + 2 * FDIM + off);
    const v4f b3 = *reinterpret_cast<const v4f*>(Bs + 3 * FDIM + off);
    const v4f beta1 = b0;
    const v4f beta2 = beta1 + b1;
    const v4f beta3 = beta2 + b2;
    sb[c] = beta3 + b3;

    const v4f w0 = *reinterpret_cast<const v4f*>(Ws + 0 * FDIM + off);
    const v4f w1 = *reinterpret_cast<const v4f*>(Ws + 1 * FDIM + off);
    const v4f w2 = *reinterpret_cast<const v4f*>(Ws + 2 * FDIM + off);
    const v4f w3 = *reinterpret_cast<const v4f*>(Ws + 3 * FDIM + off);

    d0 = fmaf(x0[c].x, w0.x, d0); d0 = fmaf(x0[c].y, w0.y, d0);
    d0 = fmaf(x0[c].z, w0.z, d0); d0 = fmaf(x0[c].w, w0.w, d0);

    d1 = fmaf(x0[c].x, w1.x, d1); d1 = fmaf(x0[c].y, w1.y, d1);
    d1 = fmaf(x0[c].z, w1.z, d1); d1 = fmaf(x0[c].w, w1.w, d1);
    e1 = fmaf(beta1.x, w1.x, e1); e1 = fmaf(beta1.y, w1.y, e1);
    e1 = fmaf(beta1.z, w1.z, e1); e1 = fmaf(beta1.w, w1.w, e1);

    d2 = fmaf(x0[c].x, w2.x, d2); d2 = fmaf(x0[c].y, w2.y, d2);
    d2 = fmaf(x0[c].z, w2.z, d2); d2 = fmaf(x0[c].w, w2.w, d2);
    e2 = fmaf(beta2.x, w2.x, e2); e2 = fmaf(beta2.y, w2.y, e2);
    e2 = fmaf(beta2.z, w2.z, e2); e2 = fmaf(beta2.w, w2.w, e2);

    d3 = fmaf(x0[c].x, w3.x, d3); d3 = fmaf(x0[c].y, w3.y, d3);
    d3 = fmaf(x0[c].z, w3.z, d3); d3 = fmaf(x0[c].w, w3.w, d3);
    e3 = fmaf(beta3.x, w3.x, e3); e3 = fmaf(beta3.y, w3.y, e3);
    e3 = fmaf(beta3.z, w3.z, e3); e3 = fmaf(beta3.w, w3.w, e3);
  }

  // one 64-lane butterfly reduce, 7-wide ILP
#pragma unroll
  for (int off = 32; off > 0; off >>= 1) {
    d0 += __shfl_xor(d0, off, 64);
    d1 += __shfl_xor(d1, off, 64);
    d2 += __shfl_xor(d2, off, 64);
    d3 += __shfl_xor(d3, off, 64);
    e1 += __shfl_xor(e1, off, 64);
    e2 += __shfl_xor(e2, off, 64);
    e3 += __shfl_xor(e3, off, 64);
  }

  // scalar alpha recursion (e0 == 0)
  float a = 1.f + d0;
  a += fmaf(a, d1, e1);
  a += fmaf(a, d2, e2);
  a += fmaf(a, d3, e3);

  float* outr = out + (size_t)row * FDIM;
#pragma unroll
  for (int c = 0; c < 4; ++c) {
    v4f r;
    r.x = fmaf(a, x0[c].x, sb[c].x);
    r.y = fmaf(a, x0[c].y, sb[c].y);
    r.z = fmaf(a, x0[c].z, sb[c].z);
    r.w = fmaf(a, x0[c].w, sb[c].w);
    __builtin_nontemporal_store(
        r, reinterpret_cast<v4f*>(outr + c * 256 + lane * 4));
  }
}

extern "C" void kernel_launch(void* const* d_in, const int* in_sizes, int n_in,
                              void* d_out, int out_size, void* d_ws, size_t ws_size,
                              hipStream_t stream) {
  const float* x  = (const float*)d_in[0];
  const float* Ws = (const float*)d_in[1];
  const float* Bs = (const float*)d_in[2];
  float* out = (float*)d_out;
  const int nrows = in_sizes[0] / FDIM;  // 32768
  const int grid = (nrows + 3) / 4;      // 4 rows (waves) per block
  hipLaunchKernelGGL(cross_net_fused, dim3(grid), dim3(256), 0, stream,
                     x, Ws, Bs, out, nrows);
}

// Round 16
// 238.563 us; speedup vs baseline: 1.0407x; 1.0407x over previous
//
#include <hip/hip_runtime.h>

#define FDIM 1024
#define NLAYERS 4

typedef float v4f __attribute__((ext_vector_type(4)));

// ---------------------------------------------------------------------------
// Algebraic form of the cross layer:
//   x_{i+1} = x0*s_i + B_i + x_i,  s_i = dot(x_i, W_i)
// =>  x_i = alpha_i * x0 + beta_i,   beta_i = sum_{k<i} B_k  (row-independent)
//     s_i = alpha_i * d_i + e_i,     d_i = dot(x0, W_i)  (per-row)
//                                    e_i = dot(beta_i, W_i)  (row-independent)
//     alpha_{i+1} = alpha_i + s_i,   alpha_0 = 1
//   out = alpha_4 * x0 + SB,         SB = beta_4 = B0+B1+B2+B3
//
// Two-kernel form (measured best: 237.9 us e2e, Round 5). Pre-kernel
// computes row-independent e1..e3 and SB once; main kernel is one pass.
// ---------------------------------------------------------------------------

// Pre-kernel: one block computes e1,e2,e3 (e0==0) and SB[1024] into d_ws.
// ws layout: ws[0..2] = e1,e2,e3 ; ws[16..16+1023] = SB.
__global__ __launch_bounds__(256) void cross_net_pre(
    const float* __restrict__ Ws, const float* __restrict__ Bs,
    float* __restrict__ ws) {
  const int t = threadIdx.x;
  __shared__ float red[3][256];
  float e1 = 0.f, e2 = 0.f, e3 = 0.f;
#pragma unroll
  for (int c = 0; c < 4; ++c) {
    const int f = c * 256 + t;
    const float B0 = Bs[0 * FDIM + f], B1 = Bs[1 * FDIM + f];
    const float B2 = Bs[2 * FDIM + f], B3 = Bs[3 * FDIM + f];
    const float W1 = Ws[1 * FDIM + f], W2 = Ws[2 * FDIM + f];
    const float W3 = Ws[3 * FDIM + f];
    const float beta1 = B0;
    const float beta2 = beta1 + B1;
    const float beta3 = beta2 + B2;
    e1 = fmaf(beta1, W1, e1);
    e2 = fmaf(beta2, W2, e2);
    e3 = fmaf(beta3, W3, e3);
    ws[16 + f] = beta3 + B3;  // SB
  }
  red[0][t] = e1; red[1][t] = e2; red[2][t] = e3;
  __syncthreads();
#pragma unroll
  for (int s = 128; s > 0; s >>= 1) {
    if (t < s) {
      red[0][t] += red[0][t + s];
      red[1][t] += red[1][t + s];
      red[2][t] += red[2][t + s];
    }
    __syncthreads();
  }
  if (t == 0) { ws[0] = red[0][0]; ws[1] = red[1][0]; ws[2] = red[2][0]; }
}

// Main kernel: one wave per row. One pass over x0 computes d0..d3, one
// 4-wide butterfly reduce, scalar alpha recursion, then out = a*x0 + SB.
__global__ __launch_bounds__(256) void cross_net_main(
    const float* __restrict__ x, const float* __restrict__ Ws,
    const float* __restrict__ ws, float* __restrict__ out, int nrows) {
  const int wave = threadIdx.x >> 6;
  const int lane = threadIdx.x & 63;
  const int row = blockIdx.x * 4 + wave;
  if (row >= nrows) return;

  const float* xr = x + (size_t)row * FDIM;
  v4f x0[4];
#pragma unroll
  for (int c = 0; c < 4; ++c)
    x0[c] = __builtin_nontemporal_load(
        reinterpret_cast<const v4f*>(xr + c * 256 + lane * 4));

  // d_j = partial dot(x0, W_j) over this lane's 16 elements
  float d[4];
#pragma unroll
  for (int j = 0; j < NLAYERS; ++j) {
    const float* W = Ws + j * FDIM;
    float s = 0.f;
#pragma unroll
    for (int c = 0; c < 4; ++c) {
      const v4f w = *reinterpret_cast<const v4f*>(W + c * 256 + lane * 4);
      s = fmaf(x0[c].x, w.x, s);
      s = fmaf(x0[c].y, w.y, s);
      s = fmaf(x0[c].z, w.z, s);
      s = fmaf(x0[c].w, w.w, s);
    }
    d[j] = s;
  }
  // one 64-lane butterfly reduce, 4-wide ILP
#pragma unroll
  for (int off = 32; off > 0; off >>= 1) {
#pragma unroll
    for (int j = 0; j < NLAYERS; ++j) d[j] += __shfl_xor(d[j], off, 64);
  }

  // scalar alpha recursion (e0 == 0)
  const float e1 = ws[0], e2 = ws[1], e3 = ws[2];
  float a = 1.f + d[0];
  a += fmaf(a, d[1], e1);
  a += fmaf(a, d[2], e2);
  a += fmaf(a, d[3], e3);

  const float* SB = ws + 16;
  float* outr = out + (size_t)row * FDIM;
#pragma unroll
  for (int c = 0; c < 4; ++c) {
    const v4f sb = *reinterpret_cast<const v4f*>(SB + c * 256 + lane * 4);
    v4f r;
    r.x = fmaf(a, x0[c].x, sb.x);
    r.y = fmaf(a, x0[c].y, sb.y);
    r.z = fmaf(a, x0[c].z, sb.z);
    r.w = fmaf(a, x0[c].w, sb.w);
    __builtin_nontemporal_store(
        r, reinterpret_cast<v4f*>(outr + c * 256 + lane * 4));
  }
}

extern "C" void kernel_launch(void* const* d_in, const int* in_sizes, int n_in,
                              void* d_out, int out_size, void* d_ws, size_t ws_size,
                              hipStream_t stream) {
  const float* x  = (const float*)d_in[0];
  const float* Ws = (const float*)d_in[1];
  const float* Bs = (const float*)d_in[2];
  float* out = (float*)d_out;
  float* ws  = (float*)d_ws;
  const int nrows = in_sizes[0] / FDIM;  // 32768
  hipLaunchKernelGGL(cross_net_pre, dim3(1), dim3(256), 0, stream, Ws, Bs, ws);
  const int grid = (nrows + 3) / 4;  // 4 rows (waves) per block
  hipLaunchKernelGGL(cross_net_main, dim3(grid), dim3(256), 0, stream,
                     x, Ws, ws, out, nrows);
}